// Round 12
// baseline (219.034 us; speedup 1.0000x reference)
//
#include <hip/hip_runtime.h>
#include <hip/hip_bf16.h>
#include <math.h>

#define F_IN 512
#define HOUT 64      // HEADS*C1
#define HEADS 8
#define C1 8
#define NCLS 40
#define NEG 0.2f

#define DPB 256            // dsts per bucket
#define CAP 8064           // staging + col capacity per bucket
#define EPT 32             // edges per thread in passA
#define WLD 520            // padded K-stride of transposed bf16 W1

typedef __attribute__((ext_vector_type(8))) short short8;
typedef __attribute__((ext_vector_type(4))) float f32x4;

__device__ __forceinline__ ushort f2b(float f) {
    union { float f; unsigned u; } v; v.f = f;
    unsigned r = (v.u + 0x7FFFu + ((v.u >> 16) & 1u)) >> 16;   // RNE
    return (ushort)r;
}
__device__ __forceinline__ float b2f(ushort b) {
    union { unsigned u; float f; } v; v.u = ((unsigned)b) << 16;
    return v.f;
}
__device__ __forceinline__ float b2f_lo(unsigned u) { union { unsigned u; float f; } v; v.u = u << 16; return v.f; }
__device__ __forceinline__ float b2f_hi(unsigned u) { union { unsigned u; float f; } v; v.u = u & 0xFFFF0000u; return v.f; }

// ---------------- prep: init ∥ wconv ∥ w2conv (block-fused) ----------------

__global__ __launch_bounds__(256) void prep_k(const float* __restrict__ W1, const float* __restrict__ W2,
                                              int* __restrict__ gcur, ushort* __restrict__ Wtg,
                                              ushort* __restrict__ W2t, int nbuck) {
    int bid = blockIdx.x, t = threadIdx.x;
    if (bid < 128) {                       // wconv: W1 -> Wtg[c][k] bf16, padded
        int idx = bid * 256 + t;
        int k = idx >> 6, c = idx & 63;
        Wtg[(size_t)c * WLD + k] = f2b(W1[idx]);
    } else if (bid < 140) {                // w2conv: W2 -> W2t[48][64] (cols>=40 zero)
        int idx = (bid - 128) * 256 + t;
        int c = idx >> 6, k = idx & 63;
        W2t[idx] = (c < NCLS) ? f2b(W2[k * NCLS + c]) : 0;
    } else {                               // init gcur
        int b = (bid - 140) * 256 + t;
        if (b < nbuck) gcur[b] = b * CAP;
    }
}

// ---------------- work1: gemm1 ∥ passA (block-fused) ----------------

__device__ void gemm1_body(int bid, const float* __restrict__ x, const ushort* __restrict__ Wtg,
                           ushort* __restrict__ h1b, int n, ushort Asd[128][40]) {
    int tid = threadIdx.x;
    int lane = tid & 63, wid = tid >> 6;
    int lr = lane & 15, lg = lane >> 4;
    int row0 = bid * 128;
    f32x4 acc[2][4];
#pragma unroll
    for (int rt = 0; rt < 2; ++rt)
#pragma unroll
        for (int ct = 0; ct < 4; ++ct) acc[rt][ct] = (f32x4){0.f, 0.f, 0.f, 0.f};

    for (int k0 = 0; k0 < F_IN; k0 += 32) {
#pragma unroll
        for (int j = 0; j < 4; ++j) {
            int idx = tid + j * 256;
            int r = idx >> 3;
            int k4 = (idx & 7) << 2;
            int gr = row0 + r;
            float4 v = (gr < n) ? *(const float4*)&x[(size_t)gr * F_IN + k0 + k4]
                                : make_float4(0.f, 0.f, 0.f, 0.f);
            ushort4 b4 = make_ushort4(f2b(v.x), f2b(v.y), f2b(v.z), f2b(v.w));
            *(ushort4*)&Asd[r][k4] = b4;
        }
        __syncthreads();
        short8 af[2], bf[4];
#pragma unroll
        for (int rt = 0; rt < 2; ++rt)
            af[rt] = *(const short8*)&Asd[wid * 32 + rt * 16 + lr][lg * 8];
#pragma unroll
        for (int ct = 0; ct < 4; ++ct)
            bf[ct] = *(const short8*)&Wtg[(size_t)(ct * 16 + lr) * WLD + k0 + lg * 8];
#pragma unroll
        for (int rt = 0; rt < 2; ++rt)
#pragma unroll
            for (int ct = 0; ct < 4; ++ct)
                acc[rt][ct] = __builtin_amdgcn_mfma_f32_16x16x32_bf16(af[rt], bf[ct], acc[rt][ct], 0, 0, 0);
        __syncthreads();
    }
#pragma unroll
    for (int rt = 0; rt < 2; ++rt)
#pragma unroll
        for (int q = 0; q < 4; ++q) {
            int gr = row0 + wid * 32 + rt * 16 + lg * 4 + q;
            if (gr < n) {
#pragma unroll
                for (int ct = 0; ct < 4; ++ct)
                    h1b[(size_t)gr * HOUT + ct * 16 + lr] = f2b(acc[rt][ct][q]);
            }
        }
}

__device__ void passA_body(int bid, const int* __restrict__ ei, int* __restrict__ gcur,
                           int* __restrict__ bkt, int E, int Etot, int nbuck,
                           int* hist, int* lbase) {
    int t = threadIdx.x;
    int base_e = bid * (256 * EPT);
    for (int j = t; j < 512; j += 256) hist[j] = 0;
    __syncthreads();
    for (int j = 0; j < EPT; ++j) {
        int idx = base_e + j * 256 + t;
        if (idx < Etot) {
            int d = (idx < E) ? ei[E + idx] : (idx - E);
            atomicAdd(&hist[d >> 8], 1);
        }
    }
    __syncthreads();
    for (int j = t; j < nbuck; j += 256) {
        int c = hist[j];
        lbase[j] = c ? atomicAdd(&gcur[j], c) : 0;
    }
    __syncthreads();
    for (int j = t; j < 512; j += 256) hist[j] = 0;
    __syncthreads();
    for (int j = 0; j < EPT; ++j) {
        int idx = base_e + j * 256 + t;
        if (idx < Etot) {
            int s, d;
            if (idx < E) { s = ei[idx]; d = ei[E + idx]; } else { s = idx - E; d = idx - E; }
            int b = d >> 8;
            int slot = atomicAdd(&hist[b], 1);
            bkt[lbase[b] + slot] = (s << 8) | (d & 255);   // packed 4B
        }
    }
}

__global__ __launch_bounds__(256) void work1_k(const float* __restrict__ x, const ushort* __restrict__ Wtg,
                                               ushort* __restrict__ h1b, int n,
                                               const int* __restrict__ ei, int* __restrict__ gcur,
                                               int* __restrict__ bkt, int E, int Etot, int nbuck, int g1) {
    __shared__ ushort Asd[128][40];
    __shared__ int hist[512];
    __shared__ int lbase[512];
    if ((int)blockIdx.x < g1) gemm1_body(blockIdx.x, x, Wtg, h1b, n, Asd);
    else passA_body(blockIdx.x - g1, ei, gcur, bkt, E, Etot, nbuck, hist, lbase);
}

// ---------------- work2: passB ∥ att1 (block-fused); passB self-based, writes rowse ----------------

__device__ void passB_body(int b, const int* __restrict__ bkt, const int* __restrict__ gcur,
                           int2* __restrict__ rowse, int* __restrict__ col, int n,
                           int* hist, int* lcur, int* wsum) {
    int t = threadIdx.x;
    int cnt = gcur[b] - b * CAP;
    int base = b * CAP;                  // fixed per-bucket col base (col padded per bucket)
    int d0 = b * DPB;
    int ndst = min(DPB, n - d0);
    const int* src = bkt + (size_t)b * CAP;
    hist[t] = 0;
    __syncthreads();
    for (int e = t; e < cnt; e += 256) {
        atomicAdd(&hist[src[e] & 255], 1);
    }
    __syncthreads();
    int v = hist[t];
    int lane = t & 63, w = t >> 6;
    int ss = v;
#pragma unroll
    for (int off = 1; off < 64; off <<= 1) { int t2 = __shfl_up(ss, off); if (lane >= off) ss += t2; }
    if (lane == 63) wsum[w] = ss;
    __syncthreads();
    int woff = 0;
    for (int j = 0; j < w; ++j) woff += wsum[j];
    int excl = woff + ss - v;
    if (t < ndst) rowse[d0 + t] = make_int2(base + excl, base + excl + v);
    lcur[t] = excl;
    __syncthreads();
    for (int e = t; e < cnt; e += 256) {
        int u = src[e];
        int pos = atomicAdd(&lcur[u & 255], 1);
        col[base + pos] = (int)((unsigned)u >> 8);
    }
}

__device__ void att1_body(int bid, const ushort* __restrict__ h1b, const float* __restrict__ asw,
                          const float* __restrict__ adw, float* __restrict__ as1,
                          float* __restrict__ ad1, int n) {
    int t = bid * 256 + threadIdx.x;
    if (t >= n * HEADS) return;
    int hd = t & 7;
    const ushort* hp = h1b + (size_t)(t >> 3) * HOUT + hd * C1;
    short8 hv = *(const short8*)hp;
    float4 a0 = *(const float4*)(asw + hd * C1), a1 = *(const float4*)(asw + hd * C1 + 4);
    float4 d0 = *(const float4*)(adw + hd * C1), d1 = *(const float4*)(adw + hd * C1 + 4);
    float h0 = b2f((ushort)hv[0]), h1 = b2f((ushort)hv[1]), h2 = b2f((ushort)hv[2]), h3 = b2f((ushort)hv[3]);
    float h4 = b2f((ushort)hv[4]), h5 = b2f((ushort)hv[5]), h6 = b2f((ushort)hv[6]), h7 = b2f((ushort)hv[7]);
    as1[t] = h0*a0.x + h1*a0.y + h2*a0.z + h3*a0.w + h4*a1.x + h5*a1.y + h6*a1.z + h7*a1.w;
    ad1[t] = h0*d0.x + h1*d0.y + h2*d0.z + h3*d0.w + h4*d1.x + h5*d1.y + h6*d1.z + h7*d1.w;
}

__global__ __launch_bounds__(256) void work2_k(const int* __restrict__ bkt, const int* __restrict__ gcur,
                                               int2* __restrict__ rowse, int* __restrict__ col, int n,
                                               const ushort* __restrict__ h1b, const float* __restrict__ asw,
                                               const float* __restrict__ adw, float* __restrict__ as1,
                                               float* __restrict__ ad1, int gpb) {
    __shared__ int hist[DPB];
    __shared__ int lcur[DPB];
    __shared__ int wsum[4];
    if ((int)blockIdx.x < gpb) passB_body(blockIdx.x, bkt, gcur, rowse, col, n, hist, lcur, wsum);
    else att1_body(blockIdx.x - gpb, h1b, asw, adw, as1, ad1, n);
}

// ---------------- fused layer-1 aggregation + g2 GEMM ----------------
// 512 threads = 8 waves; wave = 1 node pair -> block owns 16 nodes.
// hact kept in swizzled LDS tile [16][64]bf16; wave 0 runs the 64->40 MFMA GEMM after the barrier.

__global__ __launch_bounds__(512) void l1g2_k(const ushort* __restrict__ h1b, const float* __restrict__ as1,
                                              const float* __restrict__ ad1, const float* __restrict__ b1,
                                              const int2* __restrict__ rowse, const int* __restrict__ col,
                                              const ushort* __restrict__ W2t, const float* __restrict__ asw,
                                              const float* __restrict__ adw, ushort* __restrict__ h2b,
                                              float* __restrict__ as2, float* __restrict__ ad2, int n) {
    __shared__ int2 pk_all[8][2 * 273];
    __shared__ ushort hact_lds[16 * 64];      // row-swizzled: byte ^= (row&7)<<4
    int wid = threadIdx.x >> 6, lane = threadIdx.x & 63;
    int nA = (blockIdx.x * 8 + wid) * 2;
    int nB = nA + 1;
    int na = lane >> 5, sl = lane & 31;
    int node = nA + na;
    bool nodev = node < n;
    int nd = wid * 2 + na;                    // block-local node row 0..15
    int4 rr = make_int4(0, 0, 0, 0);
    if (nA < n) rr = *(const int4*)&rowse[nA];
    if (nB >= n) { rr.z = rr.y; rr.w = rr.y; }
    int degA = rr.y - rr.x, degB = rr.w - rr.z;
    int st  = na ? rr.z : rr.x;
    int deg = na ? degB : degA;
    int2* pk = pk_all[wid];

    if (degA <= 32 && degB <= 32) {
        bool v = nodev && (sl < deg);
        int s = 0;
        float4 a0 = make_float4(0.f, 0.f, 0.f, 0.f), a1 = a0;
        if (v) {
            s = col[st + sl];
            a0 = *(const float4*)&as1[s * 8];
            a1 = *(const float4*)&as1[s * 8 + 4];
        }
        float4 d0 = make_float4(0.f, 0.f, 0.f, 0.f), d1 = d0;
        if (nodev) {
            d0 = *(const float4*)&ad1[node * 8];
            d1 = *(const float4*)&ad1[node * 8 + 4];
        }
        float ea[8] = {a0.x + d0.x, a0.y + d0.y, a0.z + d0.z, a0.w + d0.w,
                       a1.x + d1.x, a1.y + d1.y, a1.z + d1.z, a1.w + d1.w};
#pragma unroll
        for (int h = 0; h < 8; ++h) {
            float e0 = ea[h];
            float ee = v ? (e0 >= 0.f ? e0 : NEG * e0) : -1e30f;
            pk[na * 273 + h * 34 + sl] = make_int2(__float_as_int(ee), s);
        }
        __asm__ volatile("s_waitcnt lgkmcnt(0)" ::: "memory");
        __builtin_amdgcn_sched_barrier(0);
        {
            int t = lane & 3, h = (lane >> 2) & 7, na2 = lane >> 5;
            int base = na2 * 273 + h * 34;
            float e[8];
#pragma unroll
            for (int u = 0; u < 8; ++u) e[u] = __int_as_float(pk[base + t + 4 * u].x);
            float mx = e[0];
#pragma unroll
            for (int u = 1; u < 8; ++u) mx = fmaxf(mx, e[u]);
            mx = fmaxf(mx, __shfl_xor(mx, 1));
            mx = fmaxf(mx, __shfl_xor(mx, 2));
            float p[8], sm = 0.f;
#pragma unroll
            for (int u = 0; u < 8; ++u) { p[u] = __expf(e[u] - mx); sm += p[u]; }
            sm += __shfl_xor(sm, 1);
            sm += __shfl_xor(sm, 2);
            float inv = 1.f / (sm + 1e-16f);
#pragma unroll
            for (int u = 0; u < 8; ++u) pk[base + t + 4 * u].x = __float_as_int(p[u] * inv);
        }
        __asm__ volatile("s_waitcnt lgkmcnt(0)" ::: "memory");
        __builtin_amdgcn_sched_barrier(0);
        // phase 3: edge-pair gather, batch-4
        int cl = sl & 15;
        int eo = sl >> 4;
        int pb = na * 273 + (cl >> 1) * 34 + eo;
        float acc0 = 0.f, acc1 = 0.f, acc2 = 0.f, acc3 = 0.f;
        int mdeg = max(degA, degB);
        for (int g0 = 0; 2 * g0 < mdeg; g0 += 4) {
            int2 qa = pk[pb + 2 * g0];
            int2 qb = pk[pb + 2 * g0 + 2];
            int2 qc = pk[pb + 2 * g0 + 4];
            int2 qd = pk[pb + 2 * g0 + 6];        // max slot 31 < 34; out-of-deg slots carry w=0
            uint2 ha = *(const uint2*)&h1b[(size_t)qa.y * HOUT + 4 * cl];
            uint2 hb = *(const uint2*)&h1b[(size_t)qb.y * HOUT + 4 * cl];
            uint2 hc = *(const uint2*)&h1b[(size_t)qc.y * HOUT + 4 * cl];
            uint2 hd = *(const uint2*)&h1b[(size_t)qd.y * HOUT + 4 * cl];
            float wa = __int_as_float(qa.x), wb = __int_as_float(qb.x);
            float wc = __int_as_float(qc.x), wd = __int_as_float(qd.x);
            acc0 += wa * b2f_lo(ha.x) + wb * b2f_lo(hb.x) + wc * b2f_lo(hc.x) + wd * b2f_lo(hd.x);
            acc1 += wa * b2f_hi(ha.x) + wb * b2f_hi(hb.x) + wc * b2f_hi(hc.x) + wd * b2f_hi(hd.x);
            acc2 += wa * b2f_lo(ha.y) + wb * b2f_lo(hb.y) + wc * b2f_lo(hc.y) + wd * b2f_lo(hd.y);
            acc3 += wa * b2f_hi(ha.y) + wb * b2f_hi(hb.y) + wc * b2f_hi(hc.y) + wd * b2f_hi(hd.y);
        }
        acc0 += __shfl_xor(acc0, 16);
        acc1 += __shfl_xor(acc1, 16);
        acc2 += __shfl_xor(acc2, 16);
        acc3 += __shfl_xor(acc3, 16);
        if (eo == 0) {
            float4 bb = *(const float4*)&b1[4 * cl];
            float o0 = acc0 + bb.x, o1 = acc1 + bb.y, o2 = acc2 + bb.z, o3 = acc3 + bb.w;
            float e0 = o0 > 0.f ? o0 : expm1f(o0);
            float e1 = o1 > 0.f ? o1 : expm1f(o1);
            float e2 = o2 > 0.f ? o2 : expm1f(o2);
            float e3 = o3 > 0.f ? o3 : expm1f(o3);
            ushort4 op = make_ushort4(f2b(e0), f2b(e1), f2b(e2), f2b(e3));
            int byte = nd * 128 + ((8 * cl) ^ ((nd & 7) << 4));
            *(ushort4*)((char*)hact_lds + byte) = op;
        }
    } else {
        // rare fallback: serial online softmax per half, 2 channels per lane
        int hd = sl >> 2;
        float ad = nodev ? ad1[node * 8 + hd] : 0.f;
        float m = -1e30f, den = 0.f, a0 = 0.f, a1 = 0.f;
        int en = st + deg;
        for (int e = st; e < en; ++e) {
            int s = col[e];
            float e0 = as1[s * 8 + hd] + ad;
            float ee = e0 >= 0.f ? e0 : NEG * e0;
            unsigned hv = *(const unsigned*)&h1b[(size_t)s * HOUT + 2 * sl];
            float mn = fmaxf(m, ee);
            float sc = __expf(m - mn), p = __expf(ee - mn);
            den = den * sc + p;
            a0 = a0 * sc + p * b2f_lo(hv);
            a1 = a1 * sc + p * b2f_hi(hv);
            m = mn;
        }
        float2 bb = *(const float2*)&b1[2 * sl];
        float o0 = a0 / (den + 1e-16f) + bb.x;
        float o1 = a1 / (den + 1e-16f) + bb.y;
        float e0 = o0 > 0.f ? o0 : expm1f(o0);
        float e1 = o1 > 0.f ? o1 : expm1f(o1);
        unsigned op = (unsigned)f2b(e0) | ((unsigned)f2b(e1) << 16);
        int byte = nd * 128 + ((4 * sl) ^ ((nd & 7) << 4));
        *(unsigned*)((char*)hact_lds + byte) = op;
    }

    __syncthreads();
    // ---- g2 phase: wave 0 computes h2 = hact @ W2 for the block's 16 rows ----
    if (wid == 0) {
        int lr = lane & 15, lg = lane >> 4;
        int row0 = blockIdx.x * 16;
        f32x4 acc[3];
#pragma unroll
        for (int ct = 0; ct < 3; ++ct) acc[ct] = (f32x4){0.f, 0.f, 0.f, 0.f};
#pragma unroll
        for (int ks = 0; ks < 2; ++ks) {
            int byte = lr * 128 + ((ks * 64 + lg * 16) ^ ((lr & 7) << 4));
            short8 af = *(const short8*)((char*)hact_lds + byte);
#pragma unroll
            for (int ct = 0; ct < 3; ++ct) {
                short8 bf = *(const short8*)&W2t[(ct * 16 + lr) * HOUT + ks * 32 + lg * 8];
                acc[ct] = __builtin_amdgcn_mfma_f32_16x16x32_bf16(af, bf, acc[ct], 0, 0, 0);
            }
        }
        float av4[4], dv4[4];
#pragma unroll
        for (int q = 0; q < 4; ++q) {
            int r = row0 + lg * 4 + q;
            bool vw = r < n;
            float av = 0.f, dv = 0.f;
#pragma unroll
            for (int ct = 0; ct < 3; ++ct) {
                int c = ct * 16 + lr;
                if (c < NCLS) {
                    float o = acc[ct][q];
                    av += o * asw[c];
                    dv += o * adw[c];
                    if (vw) h2b[(size_t)r * NCLS + c] = f2b(o);
                }
            }
            av += __shfl_xor(av, 1); av += __shfl_xor(av, 2); av += __shfl_xor(av, 4); av += __shfl_xor(av, 8);
            dv += __shfl_xor(dv, 1); dv += __shfl_xor(dv, 2); dv += __shfl_xor(dv, 4); dv += __shfl_xor(dv, 8);
            av4[q] = av; dv4[q] = dv;
        }
#pragma unroll
        for (int q = 0; q < 4; ++q) {
            int r = row0 + lg * 4 + q;
            if (lr == q && r < n) as2[r] = av4[q];
            if (lr == 8 + q && r < n) ad2[r] = dv4[q];
        }
    }
}

// ---------------- layer-2 aggregation + log_softmax: 2 nodes/wave, batch-4 ----------------

__global__ __launch_bounds__(256) void l2agg_k(const ushort* __restrict__ h2b, const float* __restrict__ as2,
                                               const float* __restrict__ ad2, const float* __restrict__ b2,
                                               const int2* __restrict__ rowse, const int* __restrict__ col,
                                               float* __restrict__ out, int n) {
    __shared__ int2 pk_all[4][2 * 40];
    int wid = threadIdx.x >> 6, lane = threadIdx.x & 63;
    int nA = (blockIdx.x * 4 + wid) * 2;
    if (nA >= n) return;
    int nB = nA + 1;
    int na = lane >> 5, sl = lane & 31;
    int node = nA + na;
    bool nodev = node < n;
    int4 rr = *(const int4*)&rowse[nA];
    if (nB >= n) { rr.z = rr.y; rr.w = rr.y; }
    int degA = rr.y - rr.x, degB = rr.w - rr.z;
    int st  = na ? rr.z : rr.x;
    int deg = na ? degB : degA;

    if (degA <= 32 && degB <= 32) {
        int2* pk = pk_all[wid];
        bool v = nodev && (sl < deg);
        int s = 0; float av = 0.f;
        if (v) { s = col[st + sl]; av = as2[s]; }
        float ad = nodev ? ad2[node] : 0.f;
        float ev = av + ad;
        float ee = v ? (ev >= 0.f ? ev : NEG * ev) : -1e30f;
        float m = ee;
        m = fmaxf(m, __shfl_xor(m, 1)); m = fmaxf(m, __shfl_xor(m, 2));
        m = fmaxf(m, __shfl_xor(m, 4)); m = fmaxf(m, __shfl_xor(m, 8));
        m = fmaxf(m, __shfl_xor(m, 16));
        float p = __expf(ee - m);
        float d = p;
        d += __shfl_xor(d, 1); d += __shfl_xor(d, 2); d += __shfl_xor(d, 4);
        d += __shfl_xor(d, 8); d += __shfl_xor(d, 16);
        float w = p / (d + 1e-16f);
        pk[na * 40 + sl] = make_int2(__float_as_int(w), s);
        __asm__ volatile("s_waitcnt lgkmcnt(0)" ::: "memory");
        __builtin_amdgcn_sched_barrier(0);
        // edge-pair gather, batch-4
        bool gact = sl < 20;
        int cl = sl % 10;
        int eo2 = gact ? (sl / 10) : 0;
        int jb = na * 40 + eo2;
        float acc0 = 0.f, acc1 = 0.f, acc2 = 0.f, acc3 = 0.f;
        int mdeg = max(degA, degB);
        for (int g0 = 0; 2 * g0 < mdeg; g0 += 4) {
            int2 qa = pk[jb + 2 * g0];
            int2 qb = pk[jb + 2 * g0 + 2];
            int2 qc = pk[jb + 2 * g0 + 4];
            int2 qd = pk[jb + 2 * g0 + 6];        // max slot 31 < 40; out-of-deg slots carry w=0
            if (gact) {
                uint2 ha = *(const uint2*)&h2b[(size_t)qa.y * NCLS + 4 * cl];
                uint2 hb = *(const uint2*)&h2b[(size_t)qb.y * NCLS + 4 * cl];
                uint2 hc = *(const uint2*)&h2b[(size_t)qc.y * NCLS + 4 * cl];
                uint2 hd = *(const uint2*)&h2b[(size_t)qd.y * NCLS + 4 * cl];
                float wa = __int_as_float(qa.x), wb = __int_as_float(qb.x);
                float wc = __int_as_float(qc.x), wd = __int_as_float(qd.x);
                acc0 += wa * b2f_lo(ha.x) + wb * b2f_lo(hb.x) + wc * b2f_lo(hc.x) + wd * b2f_lo(hd.x);
                acc1 += wa * b2f_hi(ha.x) + wb * b2f_hi(hb.x) + wc * b2f_hi(hc.x) + wd * b2f_hi(hd.x);
                acc2 += wa * b2f_lo(ha.y) + wb * b2f_lo(hb.y) + wc * b2f_lo(hc.y) + wd * b2f_lo(hd.y);
                acc3 += wa * b2f_hi(ha.y) + wb * b2f_hi(hb.y) + wc * b2f_hi(hc.y) + wd * b2f_hi(hd.y);
            }
        }
        // combine even/odd partials: lane sl<10 += lane sl+10
        int self = threadIdx.x & 63;
        float p0 = __shfl(acc0, self + 10);
        float p1 = __shfl(acc1, self + 10);
        float p2s = __shfl(acc2, self + 10);
        float p3 = __shfl(acc3, self + 10);
        bool fin = sl < 10;
        float z0, z1, z2, z3;
        if (fin) {
            float4 bb = *(const float4*)&b2[4 * cl];
            z0 = acc0 + p0 + bb.x; z1 = acc1 + p1 + bb.y;
            z2 = acc2 + p2s + bb.z; z3 = acc3 + p3 + bb.w;
        } else { z0 = z1 = z2 = z3 = -1e30f; }
        float zm = fin ? fmaxf(fmaxf(z0, z1), fmaxf(z2, z3)) : -1e30f;
        zm = fmaxf(zm, __shfl_xor(zm, 1)); zm = fmaxf(zm, __shfl_xor(zm, 2));
        zm = fmaxf(zm, __shfl_xor(zm, 4)); zm = fmaxf(zm, __shfl_xor(zm, 8));
        float ex = fin ? (__expf(z0 - zm) + __expf(z1 - zm) + __expf(z2 - zm) + __expf(z3 - zm)) : 0.f;
        ex += __shfl_xor(ex, 1); ex += __shfl_xor(ex, 2);
        ex += __shfl_xor(ex, 4); ex += __shfl_xor(ex, 8);
        float ls = logf(ex);
        if (fin && nodev) {
            float4 o = make_float4(z0 - zm - ls, z1 - zm - ls, z2 - zm - ls, z3 - zm - ls);
            *(float4*)&out[(size_t)node * NCLS + 4 * cl] = o;
        }
    } else {
        // rare fallback: serial online softmax per half, 20 lanes x 2ch (own tail)
        bool act = sl < 20;
        float z0, z1;
        float ad = nodev ? ad2[node] : 0.f;
        float m = -1e30f, den = 0.f, a0 = 0.f, a1 = 0.f;
        int en = st + deg;
        for (int e = st; e < en; ++e) {
            int s = col[e];
            float ev = as2[s] + ad;
            float ee = ev >= 0.f ? ev : NEG * ev;
            float mn = fmaxf(m, ee);
            float sc = __expf(m - mn), p = __expf(ee - mn);
            den = den * sc + p;
            if (act) {
                unsigned hv = *(const unsigned*)&h2b[(size_t)s * NCLS + 2 * sl];
                a0 = a0 * sc + p * b2f_lo(hv);
                a1 = a1 * sc + p * b2f_hi(hv);
            }
            m = mn;
        }
        if (act) {
            float2 bb = *(const float2*)&b2[2 * sl];
            z0 = a0 / (den + 1e-16f) + bb.x;
            z1 = a1 / (den + 1e-16f) + bb.y;
        } else { z0 = z1 = -1e30f; }
        float zm = fmaxf(z0, z1);
        zm = fmaxf(zm, __shfl_xor(zm, 1)); zm = fmaxf(zm, __shfl_xor(zm, 2));
        zm = fmaxf(zm, __shfl_xor(zm, 4)); zm = fmaxf(zm, __shfl_xor(zm, 8));
        zm = fmaxf(zm, __shfl_xor(zm, 16));
        float ex = act ? (__expf(z0 - zm) + __expf(z1 - zm)) : 0.f;
        ex += __shfl_xor(ex, 1); ex += __shfl_xor(ex, 2); ex += __shfl_xor(ex, 4);
        ex += __shfl_xor(ex, 8); ex += __shfl_xor(ex, 16);
        float ls = logf(ex);
        if (act && nodev) {
            float2 o = make_float2(z0 - zm - ls, z1 - zm - ls);
            *(float2*)&out[(size_t)node * NCLS + 2 * sl] = o;
        }
    }
}

// ---------------- host ----------------

extern "C" void kernel_launch(void* const* d_in, const int* in_sizes, int n_in,
                              void* d_out, int out_size, void* d_ws, size_t ws_size,
                              hipStream_t stream) {
    const float* x    = (const float*)d_in[0];
    const int*   ei   = (const int*)d_in[1];
    const float* W1   = (const float*)d_in[2];
    const float* asw1 = (const float*)d_in[3];
    const float* adw1 = (const float*)d_in[4];
    const float* b1   = (const float*)d_in[5];
    const float* W2   = (const float*)d_in[6];
    const float* asw2 = (const float*)d_in[7];
    const float* adw2 = (const float*)d_in[8];
    const float* b2   = (const float*)d_in[9];
    float* out = (float*)d_out;

    const int n = in_sizes[0] / F_IN;          // 100000
    const int E = in_sizes[1] / 2;             // 1600000
    const int Etot = E + n;
    const int nbuck = (n + DPB - 1) / DPB;     // 391
    const int npair = (n + 1) / 2;

    char* ws = (char*)d_ws;
    size_t off = 0;
    auto alloc = [&](size_t bytes) -> void* {
        void* p = ws + off;
        off = (off + bytes + 255) & ~(size_t)255;
        return p;
    };
    int*    gcur   = (int*)alloc((size_t)nbuck * 4);
    int2*   rowse  = (int2*)alloc((size_t)(n + 2) * 8);
    int*    col    = (int*)alloc((size_t)nbuck * CAP * 4);           // 12.6 MB (per-bucket padded)
    int*    bkt    = (int*)alloc((size_t)nbuck * CAP * 4);           // 12.6 MB (packed 4B)
    ushort* h1b    = (ushort*)alloc((size_t)n * HOUT * 2);           // 12.8 MB
    float*  as1    = (float*)alloc((size_t)n * HEADS * 4);
    float*  ad1    = (float*)alloc((size_t)n * HEADS * 4);
    ushort* h2b    = (ushort*)alloc((size_t)n * NCLS * 2);           // 8 MB (own buffer: l1g2 races h1b)
    float*  as2    = (float*)alloc((size_t)n * 4);
    float*  ad2    = (float*)alloc((size_t)n * 4);
    ushort* Wtg    = (ushort*)alloc((size_t)HOUT * WLD * 2);
    ushort* W2t    = (ushort*)alloc((size_t)48 * HOUT * 2);

    const int g1 = (n + 127) / 128;                       // gemm1 blocks
    const int gpa = (Etot + 256 * EPT - 1) / (256 * EPT); // passA blocks
    const int gpb = nbuck;                                // passB blocks
    const int gat = (n * HEADS + 255) / 256;              // att1 blocks
    const int g16 = (n + 15) / 16;                        // l1g2 blocks (16 nodes each)

    prep_k<<<142, 256, 0, stream>>>(W1, W2, gcur, Wtg, W2t, nbuck);
    work1_k<<<g1 + gpa, 256, 0, stream>>>(x, Wtg, h1b, n, ei, gcur, bkt, E, Etot, nbuck, g1);
    work2_k<<<gpb + gat, 256, 0, stream>>>(bkt, gcur, rowse, col, n,
                                           h1b, asw1, adw1, as1, ad1, gpb);
    l1g2_k<<<g16, 512, 0, stream>>>(h1b, as1, ad1, b1, rowse, col,
                                    W2t, asw2, adw2, h2b, as2, ad2, n);
    l2agg_k<<<(npair + 3) / 4, 256, 0, stream>>>(h2b, as2, ad2, b2, rowse, col, out, n);
}